// Round 6
// baseline (802.930 us; speedup 1.0000x reference)
//
#include <hip/hip_runtime.h>
#include <hip/hip_fp16.h>
#include <math.h>

#define BATCH 2048
#define NBAS 103
#define NPAIR 102     // pair-rows per input feature: (r, r+1), r in [0,101]
#define OUTR 243      // real output width of hidden layers
#define OUTP 256      // padded output width

typedef _Float16 half2v __attribute__((ext_vector_type(2)));

__device__ __forceinline__ float dot2(unsigned a, unsigned b, float c) {
#if __has_builtin(__builtin_amdgcn_fdot2)
    return __builtin_amdgcn_fdot2(__builtin_bit_cast(half2v, a),
                                  __builtin_bit_cast(half2v, b), c, false);
#else
    __half2 ha = __builtin_bit_cast(__half2, a), hb = __builtin_bit_cast(__half2, b);
    c = fmaf(__low2float(ha), __low2float(hb), c);
    c = fmaf(__high2float(ha), __high2float(hb), c);
    return c;
#endif
}

// ---------------- basis precompute + (fused) zeroing of the next output buffer ----------
// per (b,i) -> meta {half2 w01, half2 w23, pairoff, flat}
// u = (x+0.56)/0.02. Interval j=floor(u); nonzero basis n=j-3..j clipped to [0,102].
template <int IN>
__global__ __launch_bounds__(256) void basis_kernel(
    const float* __restrict__ xin, int xstride, uint4* __restrict__ meta,
    float4* __restrict__ zbuf)     // if non-null: first 131072 threads zero 2 MB
{
    int e = blockIdx.x * 256 + threadIdx.x;
    if (zbuf && e < (BATCH * OUTP) / 4) zbuf[e] = make_float4(0.f, 0.f, 0.f, 0.f);
    if (e >= BATCH * IN) return;
    int b = e / IN, i = e - b * IN;
    float x = xin[(size_t)b * xstride + i];
    float u = (x + 0.56f) * 50.0f;
    bool inr = (u >= 0.0f) && (u < 106.0f);
    float fj = floorf(u);
    float t = u - fj;
    int j = (int)fj;
    j = j < -1 ? -1 : (j > 106 ? 106 : j);
    float omt = 1.0f - t;
    float t2 = t * t, t3 = t2 * t;
    float w[4];
    w[0] = omt * omt * omt * (1.0f / 6.0f);
    w[1] = (3.0f * t3 - 6.0f * t2 + 4.0f) * (1.0f / 6.0f);
    w[2] = (-3.0f * t3 + 3.0f * t2 + 3.0f * t + 1.0f) * (1.0f / 6.0f);
    w[3] = t3 * (1.0f / 6.0f);
    int idx = j - 3;                       // first basis index n
    int idxc = idx < 0 ? 0 : (idx > 99 ? 99 : idx);   // clamp so idxc+3 <= 102
    int d = idx - idxc;                    // nonzero only at edges
    float wc[4];
    #pragma unroll
    for (int m = 0; m < 4; ++m) {          // weight for row idxc+m is w[(idxc+m)-idx]
        int s = m - d;
        wc[m] = (inr && s >= 0 && s < 4) ? w[s] : 0.0f;
    }
    __half2 w01 = __floats2half2_rn(wc[0], wc[1]);
    __half2 w23 = __floats2half2_rn(wc[2], wc[3]);
    uint4 m4;
    m4.x = __builtin_bit_cast(unsigned, w01);
    m4.y = __builtin_bit_cast(unsigned, w23);
    m4.z = (unsigned)((i * NPAIR + idxc) << 8);   // pair-row offset in half2/uint units
    m4.w = (unsigned)(i * NBAS + idxc);           // flat index for fp32 final layer
    meta[e] = m4;
}

// ---------------- pair-table build: sw[o][i][n] (fp32) -> pairT[i][r][o] = half2(v_r, v_{r+1})
// One block per input feature i. Phase 1: coalesced loads along n (wave = one o-row),
// into LDS tile[o][106] (53-dword stride, gcd(53,32)=1 -> conflict-free columns).
// NOTE: second write guarded with nl+64 < NBAS — writing past 106 would clobber the
// next row (R5 bug). Indices 103..105 are never read (phase 2 reads at most [102]).
// Phase 2: coalesced packed writes along o.
__global__ __launch_bounds__(256) void pairgen_kernel(
    const float* __restrict__ sw, int IN, unsigned* __restrict__ pairT)
{
    __shared__ __half tile[OUTR][106];     // 243*106*2 = 51,516 B
    int i = blockIdx.x;
    int nl = threadIdx.x & 63;
    int osub = threadIdx.x >> 6;           // 0..3 (wave index)
    for (int ob = 0; ob < OUTR; ob += 4) {
        int o = ob + osub;
        if (o < OUTR) {
            const float* p = sw + ((size_t)o * IN + i) * NBAS;
            tile[o][nl] = __float2half(p[nl]);                       // n = 0..63
            if (nl + 64 < NBAS)                                       // n = 64..102 ONLY
                tile[o][nl + 64] = __float2half(p[nl + 64]);
        }
    }
    __syncthreads();
    unsigned* dst = pairT + (size_t)i * NPAIR * 256;
    for (int idx = threadIdx.x; idx < NPAIR * 256; idx += 256) {
        int p = idx >> 8, o = idx & 255;
        unsigned lo = 0, hi = 0;
        if (o < OUTR) {
            lo = __half_as_ushort(tile[o][p]);
            hi = __half_as_ushort(tile[o][p + 1]);
        }
        dst[idx] = lo | (hi << 16);
    }
}

// ---------------- fused KAN layer (spline path + residual + optional base path) ----------------
// Block = 256 threads (4 waves); wave handles one batch row b, lane covers o = lane*4..lane*4+3.
// grid = (8, BATCH/4): blockIdx.x is the i-slice (8-way split). With gridDim.x == 8 the
// linear block id % 8 == slice -> all blocks of a slice land on one XCD, whose 4 MiB L2
// holds that slice's ~3.2 MB of pairT. Partials via atomicAdd into pre-zeroed output.
template <int IN, bool RES>
__global__ __launch_bounds__(256, 8) void layer_kernel(
    const unsigned* __restrict__ pairT, const uint4* __restrict__ meta,
    const float* __restrict__ h_in, int hstride,
    const float* __restrict__ bw,
    const float* __restrict__ wbp, const float* __restrict__ wsp,
    float* __restrict__ out)
{
    const int lane = threadIdx.x & 63;
    const int wave = __builtin_amdgcn_readfirstlane(threadIdx.x >> 6);
    const int b = blockIdx.y * 4 + wave;
    const int cx = blockIdx.x;             // i-slice = XCD id
    const int i0 = (IN * cx) >> 3;
    const int i1 = (IN * (cx + 1)) >> 3;
    const uint4* mp = meta + (size_t)b * IN;
    float acc[4] = {0.f, 0.f, 0.f, 0.f};
    #pragma unroll 2
    for (int i = i0; i < i1; ++i) {
        uint4 m = mp[i];                               // wave-uniform
        const uint4* pA = (const uint4*)(pairT + m.z) + lane;
        uint4 ra = pA[0];                              // pair (r0, r0+1), this lane's 4 outputs
        uint4 rb = pA[128];                            // pair (r0+2, r0+3) (+2 rows = +512 uints)
        acc[0] = dot2(m.x, ra.x, acc[0]);
        acc[1] = dot2(m.x, ra.y, acc[1]);
        acc[2] = dot2(m.x, ra.z, acc[2]);
        acc[3] = dot2(m.x, ra.w, acc[3]);
        acc[0] = dot2(m.y, rb.x, acc[0]);
        acc[1] = dot2(m.y, rb.y, acc[1]);
        acc[2] = dot2(m.y, rb.z, acc[2]);
        acc[3] = dot2(m.y, rb.w, acc[3]);
    }
    float wsv = wsp[0];
    float wbv = wbp[0];
    #pragma unroll
    for (int c = 0; c < 4; ++c) {
        int o = lane * 4 + c;
        float v = wsv * acc[c];
        if (RES && cx == 0) v += h_in[(size_t)b * hstride + o];
        if (wbv != 0.0f && o < OUTR) {   // base path: never taken for given inputs (wb==0)
            float bs = 0.0f;
            for (int i = i0; i < i1; ++i) {
                float xx = h_in[(size_t)b * hstride + i];
                bs = fmaf(xx / (1.0f + expf(-xx)), bw[o * IN + i], bs);
            }
            v += wbv * bs;
        }
        unsafeAtomicAdd(&out[(size_t)b * OUTP + o], v);
    }
}

// ---------------- final layer 243 -> 1 ----------------
__global__ __launch_bounds__(256) void final_kernel(
    const float* __restrict__ sw5,          // (243*103,) original fp32 layout
    const uint4* __restrict__ meta,
    const float* __restrict__ h, const float* __restrict__ bw5,
    const float* __restrict__ wbp, const float* __restrict__ wsp,
    float* __restrict__ out)
{
    int wave = threadIdx.x >> 6, lane = threadIdx.x & 63;
    int b = blockIdx.x * 4 + wave;
    float s = 0.0f;
    for (int i = lane; i < OUTR; i += 64) {
        uint4 m = meta[(size_t)b * OUTR + i];
        __half2 w01 = __builtin_bit_cast(__half2, m.x);
        __half2 w23 = __builtin_bit_cast(__half2, m.y);
        const float* p = sw5 + m.w;
        s += __low2float(w01) * p[0] + __high2float(w01) * p[1]
           + __low2float(w23) * p[2] + __high2float(w23) * p[3];
    }
    #pragma unroll
    for (int d = 32; d; d >>= 1) s += __shfl_down(s, d, 64);
    if (lane == 0) {
        float v = wsp[0] * s;
        float wbv = wbp[0];
        if (wbv != 0.0f) {
            float bs = 0.0f;
            for (int i = 0; i < OUTR; ++i) {
                float xx = h[(size_t)b * OUTP + i];
                bs = fmaf(xx / (1.0f + expf(-xx)), bw5[i], bs);
            }
            v += wbv * bs;
        }
        out[b] = v;
    }
}

extern "C" void kernel_launch(void* const* d_in, const int* in_sizes, int n_in,
                              void* d_out, int out_size, void* d_ws, size_t ws_size,
                              hipStream_t stream)
{
    const float* x = (const float*)d_in[0];
    const float *bw[6], *sw[6], *wb[6], *ws[6];
    for (int l = 0; l < 6; ++l) {
        bw[l] = (const float*)d_in[1 + 4 * l];
        sw[l] = (const float*)d_in[2 + 4 * l];
        wb[l] = (const float*)d_in[3 + 4 * l];
        ws[l] = (const float*)d_in[4 + 4 * l];
    }
    // workspace layout (byte offsets)
    char* base = (char*)d_ws;
    const size_t PAIR_B = 0;                 // 243*102*256*4 = 25,380,864
    const size_t META_B = 25380864;          // 2048*243*16   =  7,962,624
    const size_t HA_B   = 33343488;          // 2048*256*4    =  2,097,152
    const size_t HB_B   = 35440640;          //                 2,097,152 -> end 37,537,792
    if (ws_size < (size_t)37537792) return;
    unsigned* pairT = (unsigned*)(base + PAIR_B);
    uint4*    meta  = (uint4*)(base + META_B);
    float*    hA    = (float*)(base + HA_B);
    float*    hB    = (float*)(base + HB_B);
    float*    outp  = (float*)d_out;

    // ---- layer 0: 64 -> 243, no residual ----
    pairgen_kernel<<<64, 256, 0, stream>>>(sw[0], 64, pairT);
    basis_kernel<64><<<(BATCH * 64) / 256, 256, 0, stream>>>(x, 64, meta, (float4*)hA);
    layer_kernel<64, false><<<dim3(8, BATCH / 4), 256, 0, stream>>>(
        pairT, meta, x, 64, bw[0], wb[0], ws[0], hA);

    // ---- layers 1..4: 243 -> 243, residual ----
    float* hin = hA; float* hout = hB;
    for (int l = 1; l <= 4; ++l) {
        pairgen_kernel<<<OUTR, 256, 0, stream>>>(sw[l], OUTR, pairT);
        basis_kernel<243><<<(BATCH * OUTR + 255) / 256, 256, 0, stream>>>(
            hin, OUTP, meta, (float4*)hout);   // also zeroes hout (dead ping-pong buffer)
        layer_kernel<243, true><<<dim3(8, BATCH / 4), 256, 0, stream>>>(
            pairT, meta, hin, OUTP, bw[l], wb[l], ws[l], hout);
        float* tmp = hin; hin = hout; hout = tmp;
    }

    // ---- layer 5: 243 -> 1, no residual ----
    basis_kernel<243><<<(BATCH * OUTR + 255) / 256, 256, 0, stream>>>(hin, OUTP, meta, nullptr);
    final_kernel<<<BATCH / 4, 256, 0, stream>>>(sw[5], meta, hin, bw[5], wb[5], ws[5], outp);
}

// Round 7
// 670.172 us; speedup vs baseline: 1.1981x; 1.1981x over previous
//
#include <hip/hip_runtime.h>
#include <hip/hip_fp16.h>
#include <math.h>

#define BATCH 2048
#define NBAS 103
#define NPAIR 102     // pair-rows per input feature: (r, r+1), r in [0,101]
#define OUTR 243      // real output width of hidden layers
#define OUTP 256      // padded output width

typedef _Float16 half2v __attribute__((ext_vector_type(2)));

__device__ __forceinline__ float dot2(unsigned a, unsigned b, float c) {
#if __has_builtin(__builtin_amdgcn_fdot2)
    return __builtin_amdgcn_fdot2(__builtin_bit_cast(half2v, a),
                                  __builtin_bit_cast(half2v, b), c, false);
#else
    __half2 ha = __builtin_bit_cast(__half2, a), hb = __builtin_bit_cast(__half2, b);
    c = fmaf(__low2float(ha), __low2float(hb), c);
    c = fmaf(__high2float(ha), __high2float(hb), c);
    return c;
#endif
}

// ---------------- shared spline-eval: (x, i) -> meta {half2 w01, half2 w23, pairoff, flat}
// u = (x+0.56)/0.02. Interval j=floor(u); nonzero basis n=j-3..j clipped to [0,102].
__device__ __forceinline__ uint4 make_meta(float x, int i) {
    float u = (x + 0.56f) * 50.0f;
    bool inr = (u >= 0.0f) && (u < 106.0f);
    float fj = floorf(u);
    float t = u - fj;
    int j = (int)fj;
    j = j < -1 ? -1 : (j > 106 ? 106 : j);
    float omt = 1.0f - t;
    float t2 = t * t, t3 = t2 * t;
    float w[4];
    w[0] = omt * omt * omt * (1.0f / 6.0f);
    w[1] = (3.0f * t3 - 6.0f * t2 + 4.0f) * (1.0f / 6.0f);
    w[2] = (-3.0f * t3 + 3.0f * t2 + 3.0f * t + 1.0f) * (1.0f / 6.0f);
    w[3] = t3 * (1.0f / 6.0f);
    int idx = j - 3;                       // first basis index n
    int idxc = idx < 0 ? 0 : (idx > 99 ? 99 : idx);   // clamp so idxc+3 <= 102
    int d = idx - idxc;                    // nonzero only at edges
    float wc[4];
    #pragma unroll
    for (int m = 0; m < 4; ++m) {          // weight for row idxc+m is w[(idxc+m)-idx]
        int s = m - d;
        wc[m] = (inr && s >= 0 && s < 4) ? w[s] : 0.0f;
    }
    __half2 w01 = __floats2half2_rn(wc[0], wc[1]);
    __half2 w23 = __floats2half2_rn(wc[2], wc[3]);
    uint4 m4;
    m4.x = __builtin_bit_cast(unsigned, w01);
    m4.y = __builtin_bit_cast(unsigned, w23);
    m4.z = (unsigned)((i * NPAIR + idxc) << 8);   // pair-row offset in half2/uint units
    m4.w = (unsigned)(i * NBAS + idxc);           // flat index for fp32 final layer
    return m4;
}

// ---------------- basis from a plain activation buffer (+ optional fused zeroing; fallback) --
template <int IN>
__global__ __launch_bounds__(256) void basis_kernel(
    const float* __restrict__ xin, int xstride, uint4* __restrict__ meta,
    float4* __restrict__ zbuf)     // if non-null: first 131072 threads zero 2 MB
{
    int e = blockIdx.x * 256 + threadIdx.x;
    if (zbuf && e < (BATCH * OUTP) / 4) zbuf[e] = make_float4(0.f, 0.f, 0.f, 0.f);
    if (e >= BATCH * IN) return;
    int b = e / IN, i = e - b * IN;
    meta[e] = make_meta(xin[(size_t)b * xstride + i], i);
}

// ---------------- basis + 8-way partial reduction + residual (new path) ----------------
// h[b][i] = (ADDRES ? hprev : 0) + sum_s parts[s][b][i]; writes hcomb and meta.
template <bool ADDRES>
__global__ __launch_bounds__(256) void basis_mid_kernel(
    const float* __restrict__ hprev,        // stride OUTP (unused if !ADDRES)
    const float* __restrict__ parts,        // 8 buffers of BATCH*OUTP floats
    uint4* __restrict__ meta, float* __restrict__ hcomb)
{
    int e = blockIdx.x * 256 + threadIdx.x;
    if (e >= BATCH * OUTR) return;
    int b = e / OUTR, i = e - b * OUTR;
    size_t addr = (size_t)b * OUTP + i;
    const size_t PS = (size_t)BATCH * OUTP;
    float h = ADDRES ? hprev[addr] : 0.0f;
    #pragma unroll
    for (int s = 0; s < 8; ++s) h += parts[s * PS + addr];
    hcomb[addr] = h;
    meta[e] = make_meta(h, i);
}

// ---------------- pair-table build: sw[o][i][n] (fp32) -> pairT[i][r][o] = half2(v_r, v_{r+1})
__global__ __launch_bounds__(256) void pairgen_kernel(
    const float* __restrict__ sw, int IN, unsigned* __restrict__ pairT)
{
    __shared__ __half tile[OUTR][106];     // 243*106*2 = 51,516 B
    int i = blockIdx.x;
    int nl = threadIdx.x & 63;
    int osub = threadIdx.x >> 6;           // 0..3 (wave index)
    for (int ob = 0; ob < OUTR; ob += 4) {
        int o = ob + osub;
        if (o < OUTR) {
            const float* p = sw + ((size_t)o * IN + i) * NBAS;
            tile[o][nl] = __float2half(p[nl]);                       // n = 0..63
            if (nl + 64 < NBAS)                                       // n = 64..102 ONLY
                tile[o][nl + 64] = __float2half(p[nl + 64]);
        }
    }
    __syncthreads();
    unsigned* dst = pairT + (size_t)i * NPAIR * 256;
    for (int idx = threadIdx.x; idx < NPAIR * 256; idx += 256) {
        int p = idx >> 8, o = idx & 255;
        unsigned lo = 0, hi = 0;
        if (o < OUTR) {
            lo = __half_as_ushort(tile[o][p]);
            hi = __half_as_ushort(tile[o][p + 1]);
        }
        dst[idx] = lo | (hi << 16);
    }
}

// ---------------- NEW layer kernel: XCD-pinned gather, plain stores to private partials ------
// Block = 256 threads (4 waves); wave handles TWO batch rows, lane covers o = lane*4..+3.
// grid = (8, BATCH/8): blockIdx.x = i-slice (8-way). Linear block id % 8 == slice ->
// slice pinned to one XCD whose L2 holds its ~3.2 MB of pairT. Slice cx stores to its own
// partial buffer part + cx*BATCH*OUTP -- no atomics, no zero-init, full-line stores.
template <int IN>
__global__ __launch_bounds__(256, 8) void layer_store_kernel(
    const unsigned* __restrict__ pairT, const uint4* __restrict__ meta,
    const float* __restrict__ h_in, int hstride,
    const float* __restrict__ bw,
    const float* __restrict__ wbp, const float* __restrict__ wsp,
    float* __restrict__ part)
{
    const int lane = threadIdx.x & 63;
    const int wave = threadIdx.x >> 6;
    const int b0 = blockIdx.y * 8 + wave * 2;
    const int cx = blockIdx.x;             // i-slice = XCD id
    const int i0 = (IN * cx) >> 3;
    const int i1 = (IN * (cx + 1)) >> 3;
    const uint4* mp0 = meta + (size_t)b0 * IN;
    const uint4* mp1 = mp0 + IN;
    float a0[4] = {0.f, 0.f, 0.f, 0.f};
    float a1[4] = {0.f, 0.f, 0.f, 0.f};
    #pragma unroll 2
    for (int i = i0; i < i1; ++i) {
        uint4 m0 = mp0[i];                             // wave-uniform (s_load)
        uint4 m1 = mp1[i];
        const uint4* pA = (const uint4*)(pairT + m0.z) + lane;
        const uint4* pB = (const uint4*)(pairT + m1.z) + lane;
        uint4 ra = pA[0];                              // b0: pair (r0, r0+1)
        uint4 rb = pA[128];                            // b0: pair (r0+2, r0+3)
        uint4 rc = pB[0];                              // b0+1 likewise
        uint4 rd = pB[128];
        a0[0] = dot2(m0.x, ra.x, a0[0]); a0[1] = dot2(m0.x, ra.y, a0[1]);
        a0[2] = dot2(m0.x, ra.z, a0[2]); a0[3] = dot2(m0.x, ra.w, a0[3]);
        a0[0] = dot2(m0.y, rb.x, a0[0]); a0[1] = dot2(m0.y, rb.y, a0[1]);
        a0[2] = dot2(m0.y, rb.z, a0[2]); a0[3] = dot2(m0.y, rb.w, a0[3]);
        a1[0] = dot2(m1.x, rc.x, a1[0]); a1[1] = dot2(m1.x, rc.y, a1[1]);
        a1[2] = dot2(m1.x, rc.z, a1[2]); a1[3] = dot2(m1.x, rc.w, a1[3]);
        a1[0] = dot2(m1.y, rd.x, a1[0]); a1[1] = dot2(m1.y, rd.y, a1[1]);
        a1[2] = dot2(m1.y, rd.z, a1[2]); a1[3] = dot2(m1.y, rd.w, a1[3]);
    }
    float wsv = wsp[0];
    float wbv = wbp[0];
    float4 v0 = make_float4(wsv * a0[0], wsv * a0[1], wsv * a0[2], wsv * a0[3]);
    float4 v1 = make_float4(wsv * a1[0], wsv * a1[1], wsv * a1[2], wsv * a1[3]);
    if (wbv != 0.0f) {                     // base path: never taken for given inputs (wb==0)
        float* pv0 = &v0.x; float* pv1 = &v1.x;
        for (int c = 0; c < 4; ++c) {
            int o = lane * 4 + c;
            if (o < OUTR) {
                float bs0 = 0.0f, bs1 = 0.0f;
                for (int i = i0; i < i1; ++i) {
                    float x0 = h_in[(size_t)b0 * hstride + i];
                    float x1 = h_in[(size_t)(b0 + 1) * hstride + i];
                    bs0 = fmaf(x0 / (1.0f + expf(-x0)), bw[o * IN + i], bs0);
                    bs1 = fmaf(x1 / (1.0f + expf(-x1)), bw[o * IN + i], bs1);
                }
                pv0[c] += wbv * bs0;
                pv1[c] += wbv * bs1;
            }
        }
    }
    float* d0 = part + ((size_t)cx * BATCH + b0) * OUTP + lane * 4;
    *(float4*)d0 = v0;
    *(float4*)(d0 + OUTP) = v1;
}

// ---------------- FALLBACK layer kernel (R6 atomic version, needs only 37.5 MB ws) ----------
template <int IN, bool RES>
__global__ __launch_bounds__(256, 8) void layer_atomic_kernel(
    const unsigned* __restrict__ pairT, const uint4* __restrict__ meta,
    const float* __restrict__ h_in, int hstride,
    const float* __restrict__ bw,
    const float* __restrict__ wbp, const float* __restrict__ wsp,
    float* __restrict__ out)
{
    const int lane = threadIdx.x & 63;
    const int wave = __builtin_amdgcn_readfirstlane(threadIdx.x >> 6);
    const int b = blockIdx.y * 4 + wave;
    const int cx = blockIdx.x;
    const int i0 = (IN * cx) >> 3;
    const int i1 = (IN * (cx + 1)) >> 3;
    const uint4* mp = meta + (size_t)b * IN;
    float acc[4] = {0.f, 0.f, 0.f, 0.f};
    #pragma unroll 2
    for (int i = i0; i < i1; ++i) {
        uint4 m = mp[i];
        const uint4* pA = (const uint4*)(pairT + m.z) + lane;
        uint4 ra = pA[0];
        uint4 rb = pA[128];
        acc[0] = dot2(m.x, ra.x, acc[0]); acc[1] = dot2(m.x, ra.y, acc[1]);
        acc[2] = dot2(m.x, ra.z, acc[2]); acc[3] = dot2(m.x, ra.w, acc[3]);
        acc[0] = dot2(m.y, rb.x, acc[0]); acc[1] = dot2(m.y, rb.y, acc[1]);
        acc[2] = dot2(m.y, rb.z, acc[2]); acc[3] = dot2(m.y, rb.w, acc[3]);
    }
    float wsv = wsp[0];
    float wbv = wbp[0];
    #pragma unroll
    for (int c = 0; c < 4; ++c) {
        int o = lane * 4 + c;
        float v = wsv * acc[c];
        if (RES && cx == 0) v += h_in[(size_t)b * hstride + o];
        if (wbv != 0.0f && o < OUTR) {
            float bs = 0.0f;
            for (int i = i0; i < i1; ++i) {
                float xx = h_in[(size_t)b * hstride + i];
                bs = fmaf(xx / (1.0f + expf(-xx)), bw[o * IN + i], bs);
            }
            v += wbv * bs;
        }
        unsafeAtomicAdd(&out[(size_t)b * OUTP + o], v);
    }
}

// ---------------- final layer 243 -> 1 ----------------
__global__ __launch_bounds__(256) void final_kernel(
    const float* __restrict__ sw5,          // (243*103,) original fp32 layout
    const uint4* __restrict__ meta,
    const float* __restrict__ h, const float* __restrict__ bw5,
    const float* __restrict__ wbp, const float* __restrict__ wsp,
    float* __restrict__ out)
{
    int wave = threadIdx.x >> 6, lane = threadIdx.x & 63;
    int b = blockIdx.x * 4 + wave;
    float s = 0.0f;
    for (int i = lane; i < OUTR; i += 64) {
        uint4 m = meta[(size_t)b * OUTR + i];
        __half2 w01 = __builtin_bit_cast(__half2, m.x);
        __half2 w23 = __builtin_bit_cast(__half2, m.y);
        const float* p = sw5 + m.w;
        s += __low2float(w01) * p[0] + __high2float(w01) * p[1]
           + __low2float(w23) * p[2] + __high2float(w23) * p[3];
    }
    #pragma unroll
    for (int d = 32; d; d >>= 1) s += __shfl_down(s, d, 64);
    if (lane == 0) {
        float v = wsp[0] * s;
        float wbv = wbp[0];
        if (wbv != 0.0f) {
            float bs = 0.0f;
            for (int i = 0; i < OUTR; ++i) {
                float xx = h[(size_t)b * OUTP + i];
                bs = fmaf(xx / (1.0f + expf(-xx)), bw5[i], bs);
            }
            v += wbv * bs;
        }
        out[b] = v;
    }
}

extern "C" void kernel_launch(void* const* d_in, const int* in_sizes, int n_in,
                              void* d_out, int out_size, void* d_ws, size_t ws_size,
                              hipStream_t stream)
{
    const float* x = (const float*)d_in[0];
    const float *bw[6], *sw[6], *wb[6], *ws[6];
    for (int l = 0; l < 6; ++l) {
        bw[l] = (const float*)d_in[1 + 4 * l];
        sw[l] = (const float*)d_in[2 + 4 * l];
        wb[l] = (const float*)d_in[3 + 4 * l];
        ws[l] = (const float*)d_in[4 + 4 * l];
    }
    char* base = (char*)d_ws;
    const size_t PAIR_B = 0;                 // 243*102*256*4 = 25,380,864
    const size_t META_B = 25380864;          // 2048*243*16   =  7,962,624
    unsigned* pairT = (unsigned*)(base + PAIR_B);
    uint4*    meta  = (uint4*)(base + META_B);
    float*    outp  = (float*)d_out;

    const size_t NEED_NEW = 54315008;        // + parts 16 MB + 2x hcomb
    const int NB243 = (BATCH * OUTR + 255) / 256;

    if (ws_size >= NEED_NEW) {
        // ---------- new path: private partials + fused reduction, no atomics ----------
        float* parts = (float*)(base + 33343488);   // 8 * 2 MB
        float* hcA   = (float*)(base + 50120704);   // 2 MB
        float* hcB   = (float*)(base + 52217856);   // 2 MB

        // layer 0: 64 -> 243
        pairgen_kernel<<<64, 256, 0, stream>>>(sw[0], 64, pairT);
        basis_kernel<64><<<(BATCH * 64) / 256, 256, 0, stream>>>(x, 64, meta, nullptr);
        layer_store_kernel<64><<<dim3(8, BATCH / 8), 256, 0, stream>>>(
            pairT, meta, x, 64, bw[0], wb[0], ws[0], parts);

        // layers 1..4: 243 -> 243 (residual folded into basis_mid of the NEXT stage)
        float* hin = hcA; float* hout = hcB;   // hin = h_{l-1} carrier
        for (int l = 1; l <= 4; ++l) {
            pairgen_kernel<<<OUTR, 256, 0, stream>>>(sw[l], OUTR, pairT);
            if (l == 1)
                basis_mid_kernel<false><<<NB243, 256, 0, stream>>>(nullptr, parts, meta, hin);
            else {
                basis_mid_kernel<true><<<NB243, 256, 0, stream>>>(hout, parts, meta, hin);
            }
            // note: for l>=2, previous h is in hout (swapped below); meta/hcomb for layer l in hin
            layer_store_kernel<243><<<dim3(8, BATCH / 8), 256, 0, stream>>>(
                pairT, meta, hin, OUTP, bw[l], wb[l], ws[l], parts);
            float* tmp = hin; hin = hout; hout = tmp;   // hout now holds h_{l}
        }
        // basis for final layer: h5 = h4 + sum(parts of layer 4); h4 is in hout
        basis_mid_kernel<true><<<NB243, 256, 0, stream>>>(hout, parts, meta, hin);
        final_kernel<<<BATCH / 4, 256, 0, stream>>>(sw[5], meta, hin, bw[5], wb[5], ws[5], outp);
    } else {
        // ---------- fallback: proven R6 path (atomics), needs 37,537,792 B ----------
        if (ws_size < (size_t)37537792) return;
        float* hA = (float*)(base + 33343488);
        float* hB = (float*)(base + 35440640);
        pairgen_kernel<<<64, 256, 0, stream>>>(sw[0], 64, pairT);
        basis_kernel<64><<<(BATCH * 64) / 256, 256, 0, stream>>>(x, 64, meta, (float4*)hA);
        layer_atomic_kernel<64, false><<<dim3(8, BATCH / 4), 256, 0, stream>>>(
            pairT, meta, x, 64, bw[0], wb[0], ws[0], hA);
        float* hin = hA; float* hout = hB;
        for (int l = 1; l <= 4; ++l) {
            pairgen_kernel<<<OUTR, 256, 0, stream>>>(sw[l], OUTR, pairT);
            basis_kernel<243><<<NB243, 256, 0, stream>>>(hin, OUTP, meta, (float4*)hout);
            layer_atomic_kernel<243, true><<<dim3(8, BATCH / 4), 256, 0, stream>>>(
                pairT, meta, hin, OUTP, bw[l], wb[l], ws[l], hout);
            float* tmp = hin; hin = hout; hout = tmp;
        }
        basis_kernel<243><<<NB243, 256, 0, stream>>>(hin, OUTP, meta, nullptr);
        final_kernel<<<BATCH / 4, 256, 0, stream>>>(sw[5], meta, hin, bw[5], wb[5], ws[5], outp);
    }
}

// Round 8
// 466.286 us; speedup vs baseline: 1.7220x; 1.4373x over previous
//
#include <hip/hip_runtime.h>
#include <hip/hip_fp16.h>
#include <math.h>

#define BATCH 2048
#define NBAS 103
#define NPAIR 102     // pair-rows per input feature: (r, r+1), r in [0,101]
#define OUTR 243      // real output width of hidden layers
#define OUTP 256      // padded output width

typedef _Float16 half2v __attribute__((ext_vector_type(2)));

__device__ __forceinline__ float dot2(unsigned a, unsigned b, float c) {
#if __has_builtin(__builtin_amdgcn_fdot2)
    return __builtin_amdgcn_fdot2(__builtin_bit_cast(half2v, a),
                                  __builtin_bit_cast(half2v, b), c, false);
#else
    __half2 ha = __builtin_bit_cast(__half2, a), hb = __builtin_bit_cast(__half2, b);
    c = fmaf(__low2float(ha), __low2float(hb), c);
    c = fmaf(__high2float(ha), __high2float(hb), c);
    return c;
#endif
}

// ---------------- shared spline-eval: (x, i) -> meta {half2 w01, half2 w23, pairoff, flat}
// u = (x+0.56)/0.02. Interval j=floor(u); nonzero basis n=j-3..j clipped to [0,102].
__device__ __forceinline__ uint4 make_meta(float x, int i) {
    float u = (x + 0.56f) * 50.0f;
    bool inr = (u >= 0.0f) && (u < 106.0f);
    float fj = floorf(u);
    float t = u - fj;
    int j = (int)fj;
    j = j < -1 ? -1 : (j > 106 ? 106 : j);
    float omt = 1.0f - t;
    float t2 = t * t, t3 = t2 * t;
    float w[4];
    w[0] = omt * omt * omt * (1.0f / 6.0f);
    w[1] = (3.0f * t3 - 6.0f * t2 + 4.0f) * (1.0f / 6.0f);
    w[2] = (-3.0f * t3 + 3.0f * t2 + 3.0f * t + 1.0f) * (1.0f / 6.0f);
    w[3] = t3 * (1.0f / 6.0f);
    int idx = j - 3;                       // first basis index n
    int idxc = idx < 0 ? 0 : (idx > 99 ? 99 : idx);   // clamp so idxc+3 <= 102
    int d = idx - idxc;                    // nonzero only at edges
    float wc[4];
    #pragma unroll
    for (int m = 0; m < 4; ++m) {          // weight for row idxc+m is w[(idxc+m)-idx]
        int s = m - d;
        wc[m] = (inr && s >= 0 && s < 4) ? w[s] : 0.0f;
    }
    __half2 w01 = __floats2half2_rn(wc[0], wc[1]);
    __half2 w23 = __floats2half2_rn(wc[2], wc[3]);
    uint4 m4;
    m4.x = __builtin_bit_cast(unsigned, w01);
    m4.y = __builtin_bit_cast(unsigned, w23);
    m4.z = (unsigned)((i * NPAIR + idxc) << 8);   // pair-row offset in half2/uint units
    m4.w = (unsigned)(i * NBAS + idxc);           // flat index for fp32 final layer
    return m4;
}

// ---------------- basis from a plain activation buffer (+ optional fused zeroing; fallback) --
template <int IN>
__global__ __launch_bounds__(256) void basis_kernel(
    const float* __restrict__ xin, int xstride, uint4* __restrict__ meta,
    float4* __restrict__ zbuf)     // if non-null: first 131072 threads zero 2 MB
{
    int e = blockIdx.x * 256 + threadIdx.x;
    if (zbuf && e < (BATCH * OUTP) / 4) zbuf[e] = make_float4(0.f, 0.f, 0.f, 0.f);
    if (e >= BATCH * IN) return;
    int b = e / IN, i = e - b * IN;
    meta[e] = make_meta(xin[(size_t)b * xstride + i], i);
}

// ---------------- basis + 8-way partial reduction + residual (new path) ----------------
// h[b][i] = (ADDRES ? hprev : 0) + sum_s parts[s][b][i]; writes hcomb and meta.
template <bool ADDRES>
__global__ __launch_bounds__(256) void basis_mid_kernel(
    const float* __restrict__ hprev,        // stride OUTP (unused if !ADDRES)
    const float* __restrict__ parts,        // 8 buffers of BATCH*OUTP floats
    uint4* __restrict__ meta, float* __restrict__ hcomb)
{
    int e = blockIdx.x * 256 + threadIdx.x;
    if (e >= BATCH * OUTR) return;
    int b = e / OUTR, i = e - b * OUTR;
    size_t addr = (size_t)b * OUTP + i;
    const size_t PS = (size_t)BATCH * OUTP;
    float h = ADDRES ? hprev[addr] : 0.0f;
    #pragma unroll
    for (int s = 0; s < 8; ++s) h += parts[s * PS + addr];
    hcomb[addr] = h;
    meta[e] = make_meta(h, i);
}

// ---------------- pair-table build: sw[o][i][n] (fp32) -> pairT[i][r][o] = half2(v_r, v_{r+1})
// R8 re-tile: grid (IN, 8) = up to 1944 blocks. Block = (feature i, 32-row o-tile).
// Phase 1: each wave loads 8 rows (16 independent coalesced 256B loads) into
// tile[32][106] (53-dword stride, gcd(53,32)=1 -> conflict-free column reads).
// Phase 2: packed half2 writes, 128B contiguous per 32-lane group.
__global__ __launch_bounds__(256) void pairgen_kernel(
    const float* __restrict__ sw, int IN, unsigned* __restrict__ pairT)
{
    __shared__ __half tile[32][106];       // 6,784 B
    int i = blockIdx.x;
    int obase = blockIdx.y * 32;
    int nl = threadIdx.x & 63;
    int w = threadIdx.x >> 6;
    #pragma unroll
    for (int k = 0; k < 8; ++k) {
        int r = w * 8 + k;                 // local row 0..31
        int o = obase + r;
        if (o < OUTR) {
            const float* p = sw + ((size_t)o * IN + i) * NBAS;
            tile[r][nl] = __float2half(p[nl]);                        // n = 0..63
            if (nl + 64 < NBAS)                                        // n = 64..102 ONLY
                tile[r][nl + 64] = __float2half(p[nl + 64]);
        }
    }
    __syncthreads();
    unsigned* dst = pairT + (size_t)i * NPAIR * 256 + obase;
    for (int idx = threadIdx.x; idx < NPAIR * 32; idx += 256) {
        int p = idx >> 5, o = idx & 31;    // pair-row, local o
        unsigned v = 0;
        if (obase + o < OUTR) {
            unsigned lo = __half_as_ushort(tile[o][p]);
            unsigned hi = __half_as_ushort(tile[o][p + 1]);
            v = lo | (hi << 16);
        }
        dst[(size_t)p * 256 + o] = v;
    }
}

// ---------------- layer kernel: XCD-pinned gather, plain stores to private partials ------
// Block = 256 threads (4 waves); wave handles TWO batch rows, lane covers o = lane*4..+3.
// grid = (8, BATCH/8): blockIdx.x = i-slice (8-way). Linear block id % 8 == slice ->
// slice pinned to one XCD whose L2 holds its ~3.2 MB of pairT. Slice cx stores to its own
// partial buffer part + cx*BATCH*OUTP -- no atomics, no zero-init, full-line stores.
template <int IN>
__global__ __launch_bounds__(256, 8) void layer_store_kernel(
    const unsigned* __restrict__ pairT, const uint4* __restrict__ meta,
    const float* __restrict__ h_in, int hstride,
    const float* __restrict__ bw,
    const float* __restrict__ wbp, const float* __restrict__ wsp,
    float* __restrict__ part)
{
    const int lane = threadIdx.x & 63;
    const int wave = threadIdx.x >> 6;
    const int b0 = blockIdx.y * 8 + wave * 2;
    const int cx = blockIdx.x;             // i-slice = XCD id
    const int i0 = (IN * cx) >> 3;
    const int i1 = (IN * (cx + 1)) >> 3;
    const uint4* mp0 = meta + (size_t)b0 * IN;
    const uint4* mp1 = mp0 + IN;
    float a0[4] = {0.f, 0.f, 0.f, 0.f};
    float a1[4] = {0.f, 0.f, 0.f, 0.f};
    #pragma unroll 2
    for (int i = i0; i < i1; ++i) {
        uint4 m0 = mp0[i];                             // wave-uniform (s_load)
        uint4 m1 = mp1[i];
        const uint4* pA = (const uint4*)(pairT + m0.z) + lane;
        const uint4* pB = (const uint4*)(pairT + m1.z) + lane;
        uint4 ra = pA[0];                              // b0: pair (r0, r0+1)
        uint4 rb = pA[128];                            // b0: pair (r0+2, r0+3)
        uint4 rc = pB[0];                              // b0+1 likewise
        uint4 rd = pB[128];
        a0[0] = dot2(m0.x, ra.x, a0[0]); a0[1] = dot2(m0.x, ra.y, a0[1]);
        a0[2] = dot2(m0.x, ra.z, a0[2]); a0[3] = dot2(m0.x, ra.w, a0[3]);
        a0[0] = dot2(m0.y, rb.x, a0[0]); a0[1] = dot2(m0.y, rb.y, a0[1]);
        a0[2] = dot2(m0.y, rb.z, a0[2]); a0[3] = dot2(m0.y, rb.w, a0[3]);
        a1[0] = dot2(m1.x, rc.x, a1[0]); a1[1] = dot2(m1.x, rc.y, a1[1]);
        a1[2] = dot2(m1.x, rc.z, a1[2]); a1[3] = dot2(m1.x, rc.w, a1[3]);
        a1[0] = dot2(m1.y, rd.x, a1[0]); a1[1] = dot2(m1.y, rd.y, a1[1]);
        a1[2] = dot2(m1.y, rd.z, a1[2]); a1[3] = dot2(m1.y, rd.w, a1[3]);
    }
    float wsv = wsp[0];
    float wbv = wbp[0];
    float4 v0 = make_float4(wsv * a0[0], wsv * a0[1], wsv * a0[2], wsv * a0[3]);
    float4 v1 = make_float4(wsv * a1[0], wsv * a1[1], wsv * a1[2], wsv * a1[3]);
    if (wbv != 0.0f) {                     // base path: never taken for given inputs (wb==0)
        float* pv0 = &v0.x; float* pv1 = &v1.x;
        for (int c = 0; c < 4; ++c) {
            int o = lane * 4 + c;
            if (o < OUTR) {
                float bs0 = 0.0f, bs1 = 0.0f;
                for (int i = i0; i < i1; ++i) {
                    float x0 = h_in[(size_t)b0 * hstride + i];
                    float x1 = h_in[(size_t)(b0 + 1) * hstride + i];
                    bs0 = fmaf(x0 / (1.0f + expf(-x0)), bw[o * IN + i], bs0);
                    bs1 = fmaf(x1 / (1.0f + expf(-x1)), bw[o * IN + i], bs1);
                }
                pv0[c] += wbv * bs0;
                pv1[c] += wbv * bs1;
            }
        }
    }
    float* d0 = part + ((size_t)cx * BATCH + b0) * OUTP + lane * 4;
    *(float4*)d0 = v0;
    *(float4*)(d0 + OUTP) = v1;
}

// ---------------- FALLBACK layer kernel (R6 atomic version, needs only 37.5 MB ws) ----------
template <int IN, bool RES>
__global__ __launch_bounds__(256, 8) void layer_atomic_kernel(
    const unsigned* __restrict__ pairT, const uint4* __restrict__ meta,
    const float* __restrict__ h_in, int hstride,
    const float* __restrict__ bw,
    const float* __restrict__ wbp, const float* __restrict__ wsp,
    float* __restrict__ out)
{
    const int lane = threadIdx.x & 63;
    const int wave = __builtin_amdgcn_readfirstlane(threadIdx.x >> 6);
    const int b = blockIdx.y * 4 + wave;
    const int cx = blockIdx.x;
    const int i0 = (IN * cx) >> 3;
    const int i1 = (IN * (cx + 1)) >> 3;
    const uint4* mp = meta + (size_t)b * IN;
    float acc[4] = {0.f, 0.f, 0.f, 0.f};
    #pragma unroll 2
    for (int i = i0; i < i1; ++i) {
        uint4 m = mp[i];
        const uint4* pA = (const uint4*)(pairT + m.z) + lane;
        uint4 ra = pA[0];
        uint4 rb = pA[128];
        acc[0] = dot2(m.x, ra.x, acc[0]); acc[1] = dot2(m.x, ra.y, acc[1]);
        acc[2] = dot2(m.x, ra.z, acc[2]); acc[3] = dot2(m.x, ra.w, acc[3]);
        acc[0] = dot2(m.y, rb.x, acc[0]); acc[1] = dot2(m.y, rb.y, acc[1]);
        acc[2] = dot2(m.y, rb.z, acc[2]); acc[3] = dot2(m.y, rb.w, acc[3]);
    }
    float wsv = wsp[0];
    float wbv = wbp[0];
    #pragma unroll
    for (int c = 0; c < 4; ++c) {
        int o = lane * 4 + c;
        float v = wsv * acc[c];
        if (RES && cx == 0) v += h_in[(size_t)b * hstride + o];
        if (wbv != 0.0f && o < OUTR) {
            float bs = 0.0f;
            for (int i = i0; i < i1; ++i) {
                float xx = h_in[(size_t)b * hstride + i];
                bs = fmaf(xx / (1.0f + expf(-xx)), bw[o * IN + i], bs);
            }
            v += wbv * bs;
        }
        unsafeAtomicAdd(&out[(size_t)b * OUTP + o], v);
    }
}

// ---------------- final layer 243 -> 1 ----------------
__global__ __launch_bounds__(256) void final_kernel(
    const float* __restrict__ sw5,          // (243*103,) original fp32 layout
    const uint4* __restrict__ meta,
    const float* __restrict__ h, const float* __restrict__ bw5,
    const float* __restrict__ wbp, const float* __restrict__ wsp,
    float* __restrict__ out)
{
    int wave = threadIdx.x >> 6, lane = threadIdx.x & 63;
    int b = blockIdx.x * 4 + wave;
    float s = 0.0f;
    for (int i = lane; i < OUTR; i += 64) {
        uint4 m = meta[(size_t)b * OUTR + i];
        __half2 w01 = __builtin_bit_cast(__half2, m.x);
        __half2 w23 = __builtin_bit_cast(__half2, m.y);
        const float* p = sw5 + m.w;
        s += __low2float(w01) * p[0] + __high2float(w01) * p[1]
           + __low2float(w23) * p[2] + __high2float(w23) * p[3];
    }
    #pragma unroll
    for (int d = 32; d; d >>= 1) s += __shfl_down(s, d, 64);
    if (lane == 0) {
        float v = wsp[0] * s;
        float wbv = wbp[0];
        if (wbv != 0.0f) {
            float bs = 0.0f;
            for (int i = 0; i < OUTR; ++i) {
                float xx = h[(size_t)b * OUTP + i];
                bs = fmaf(xx / (1.0f + expf(-xx)), bw5[i], bs);
            }
            v += wbv * bs;
        }
        out[b] = v;
    }
}

extern "C" void kernel_launch(void* const* d_in, const int* in_sizes, int n_in,
                              void* d_out, int out_size, void* d_ws, size_t ws_size,
                              hipStream_t stream)
{
    const float* x = (const float*)d_in[0];
    const float *bw[6], *sw[6], *wb[6], *ws[6];
    for (int l = 0; l < 6; ++l) {
        bw[l] = (const float*)d_in[1 + 4 * l];
        sw[l] = (const float*)d_in[2 + 4 * l];
        wb[l] = (const float*)d_in[3 + 4 * l];
        ws[l] = (const float*)d_in[4 + 4 * l];
    }
    char* base = (char*)d_ws;
    const size_t PAIR_B = 0;                 // 243*102*256*4 = 25,380,864
    const size_t META_B = 25380864;          // 2048*243*16   =  7,962,624
    unsigned* pairT = (unsigned*)(base + PAIR_B);
    uint4*    meta  = (uint4*)(base + META_B);
    float*    outp  = (float*)d_out;

    const size_t NEED_NEW = 54315008;        // + parts 16 MB + 2x hcomb
    const int NB243 = (BATCH * OUTR + 255) / 256;

    if (ws_size >= NEED_NEW) {
        // ---------- new path: private partials + fused reduction, no atomics ----------
        float* parts = (float*)(base + 33343488);   // 8 * 2 MB
        float* hcA   = (float*)(base + 50120704);   // 2 MB
        float* hcB   = (float*)(base + 52217856);   // 2 MB

        // layer 0: 64 -> 243
        pairgen_kernel<<<dim3(64, 8), 256, 0, stream>>>(sw[0], 64, pairT);
        basis_kernel<64><<<(BATCH * 64) / 256, 256, 0, stream>>>(x, 64, meta, nullptr);
        layer_store_kernel<64><<<dim3(8, BATCH / 8), 256, 0, stream>>>(
            pairT, meta, x, 64, bw[0], wb[0], ws[0], parts);

        // layers 1..4: 243 -> 243 (residual folded into basis_mid of the NEXT stage)
        float* hin = hcA; float* hout = hcB;   // hin = h_{l-1} carrier
        for (int l = 1; l <= 4; ++l) {
            pairgen_kernel<<<dim3(OUTR, 8), 256, 0, stream>>>(sw[l], OUTR, pairT);
            if (l == 1)
                basis_mid_kernel<false><<<NB243, 256, 0, stream>>>(nullptr, parts, meta, hin);
            else {
                basis_mid_kernel<true><<<NB243, 256, 0, stream>>>(hout, parts, meta, hin);
            }
            layer_store_kernel<243><<<dim3(8, BATCH / 8), 256, 0, stream>>>(
                pairT, meta, hin, OUTP, bw[l], wb[l], ws[l], parts);
            float* tmp = hin; hin = hout; hout = tmp;   // hout now holds h_{l}
        }
        // basis for final layer: h5 = h4 + sum(parts of layer 4); h4 is in hout
        basis_mid_kernel<true><<<NB243, 256, 0, stream>>>(hout, parts, meta, hin);
        final_kernel<<<BATCH / 4, 256, 0, stream>>>(sw[5], meta, hin, bw[5], wb[5], ws[5], outp);
    } else {
        // ---------- fallback: proven R6 path (atomics), needs 37,537,792 B ----------
        if (ws_size < (size_t)37537792) return;
        float* hA = (float*)(base + 33343488);
        float* hB = (float*)(base + 35440640);
        pairgen_kernel<<<dim3(64, 8), 256, 0, stream>>>(sw[0], 64, pairT);
        basis_kernel<64><<<(BATCH * 64) / 256, 256, 0, stream>>>(x, 64, meta, (float4*)hA);
        layer_atomic_kernel<64, false><<<dim3(8, BATCH / 4), 256, 0, stream>>>(
            pairT, meta, x, 64, bw[0], wb[0], ws[0], hA);
        float* hin = hA; float* hout = hB;
        for (int l = 1; l <= 4; ++l) {
            pairgen_kernel<<<dim3(OUTR, 8), 256, 0, stream>>>(sw[l], OUTR, pairT);
            basis_kernel<243><<<NB243, 256, 0, stream>>>(hin, OUTP, meta, (float4*)hout);
            layer_atomic_kernel<243, true><<<dim3(8, BATCH / 4), 256, 0, stream>>>(
                pairT, meta, hin, OUTP, bw[l], wb[l], ws[l], hout);
            float* tmp = hin; hin = hout; hout = tmp;
        }
        basis_kernel<243><<<NB243, 256, 0, stream>>>(hin, OUTP, meta, nullptr);
        final_kernel<<<BATCH / 4, 256, 0, stream>>>(sw[5], meta, hin, bw[5], wb[5], ws[5], outp);
    }
}